// Round 9
// baseline (847.292 us; speedup 1.0000x reference)
//
#include <hip/hip_runtime.h>

#define AS1 __attribute__((address_space(1)))
#define AS3 __attribute__((address_space(3)))

typedef unsigned short u16;
typedef unsigned int u32;
typedef __attribute__((ext_vector_type(8))) _Float16 half8;
typedef __attribute__((ext_vector_type(2))) _Float16 half2v;
typedef __attribute__((ext_vector_type(4))) u16 u16x4;
typedef __attribute__((ext_vector_type(8))) u16 u16x8;
typedef __attribute__((ext_vector_type(4))) u32 u32x4;
typedef __attribute__((ext_vector_type(4))) float f32x4;
typedef __attribute__((ext_vector_type(16))) float f32x16;

__device__ __forceinline__ u16 f2h(float f) {
    _Float16 h = (_Float16)f;
    return __builtin_bit_cast(u16, h);
}

__device__ __forceinline__ u32 pk2h(float a, float b) {
    return __builtin_bit_cast(u32, __builtin_amdgcn_cvt_pkrtz(a, b));
}

__device__ __forceinline__ float fexp2(float x) {
#if __has_builtin(__builtin_amdgcn_exp2f)
    return __builtin_amdgcn_exp2f(x);
#else
    return __expf(x * 0.69314718055994531f);
#endif
}

// l += p.lo + p.hi on packed f16 (consistent with the f16 P used by PV)
__device__ __forceinline__ float dot2acc(u32 w, float acc) {
#if __has_builtin(__builtin_amdgcn_fdot2)
    half2v ones = { (_Float16)1.f, (_Float16)1.f };
    return __builtin_amdgcn_fdot2(__builtin_bit_cast(half2v, w), ones, acc, false);
#else
    half2v p = __builtin_bit_cast(half2v, w);
    return acc + (float)p[0] + (float)p[1];
#endif
}

// v_permlane32_swap_b32: a' = [a.lo32, b.lo32], b' = [a.hi32, b.hi32]
__device__ __forceinline__ void plswap(u32& a, u32& b) {
    asm("v_permlane32_swap_b32 %0, %1" : "+v"(a), "+v"(b));
}

// async global->LDS, 16B per lane. LDS dest must be waveBase + lane*16.
__device__ __forceinline__ void async16(const void* g, void* l) {
    __builtin_amdgcn_global_load_lds((AS1 void*)g, (AS3 void*)l, 16, 0, 0);
}

// ---------------- prologue: ONE fused prep dispatch ----------------
// z=0: Wq transpose (scaled), z=1: Wo transpose, z=2: Wk, z=3: Wv,
// z=4: x cast (4096 blocks x 256 thr x 8 elems).

__global__ void prep_inputs(const float* __restrict__ x, u16* __restrict__ xb,
                            const float* __restrict__ Wq, const float* __restrict__ Wk,
                            const float* __restrict__ Wv, const float* __restrict__ Wo,
                            u16* __restrict__ Wqt, u16* __restrict__ Wkvt,
                            u16* __restrict__ Wot, float qscale) {
    __shared__ float tile[32][33];
    const int z = blockIdx.z;
    if (z == 4) {
        size_t base = ((size_t)(blockIdx.y * 64 + blockIdx.x) * 256 + threadIdx.x) * 8;
        float4 v0 = *(const float4*)(x + base);
        float4 v1 = *(const float4*)(x + base + 4);
        u16x8 o = { f2h(v0.x), f2h(v0.y), f2h(v0.z), f2h(v0.w),
                    f2h(v1.x), f2h(v1.y), f2h(v1.z), f2h(v1.w) };
        *(u16x8*)(xb + base) = o;
        return;
    }
    const float* in;
    u16* out;
    int N;
    float scale = 1.f;
    if (z == 0)      { in = Wq; out = Wqt; N = 2048; scale = qscale; }
    else if (z == 1) { in = Wo; out = Wot; N = 2048; }
    else if (z == 2) { in = Wk; out = Wkvt; N = 512; }
    else             { in = Wv; out = Wkvt + (size_t)512 * 2048; N = 512; }
    const int K = 2048;
    int nb = blockIdx.x * 32, kb = blockIdx.y * 32;
    if (nb >= N) return;
    int tx = threadIdx.x & 31, ty = threadIdx.x >> 5;   // 32 x 8
#pragma unroll
    for (int r = ty; r < 32; r += 8)
        tile[r][tx] = in[(size_t)(kb + r) * N + nb + tx];
    __syncthreads();
#pragma unroll
    for (int r = ty; r < 32; r += 8)
        out[(size_t)(nb + r) * K + kb + tx] = f2h(tile[tx][r] * scale);
}

// ---------------- GEMM: C[M,N] = A[M,K] * Bt[N,K]^T ----------------
// Double-buffered global_load_lds prefetch, ONE barrier per K-step.
// XCD-aware bijective block swizzle (T1): default round-robin puts the 8
// consecutive blocks sharing one B-panel on 8 different XCD L2s (8x B
// refetch). Chunked mapping gives each XCD nwg/8 CONSECUTIVE tiles (2-3
// B-panels, 1-1.5 MB -> L2-fit). Requires nwg % 8 == 0 (768, 512: both ok).
// OUTMODE 0 = fp32 out, 1 = fp16 out, 2 = fp16 transposed,
// OUTMODE 3 = fused QKV: n<2048 -> Qb (C, ldc 2048); <2560 -> Kb (C2, ldc
//   512); else Vtb transposed (C2 + 4096*512, ldc 4096).

template <int OUTMODE>
__global__ __launch_bounds__(256, OUTMODE == 3 ? 3 : 2) void gemm_bt(
        const u16* __restrict__ A, const u16* __restrict__ Bt,
        void* __restrict__ C, void* __restrict__ C2,
        int M, int N, int K, int ldc) {
    __shared__ __align__(16) u16 As[2][128 * 32];
    __shared__ __align__(16) u16 Bs[2][128 * 32];
    // XCD swizzle: logical id = (bid%8)*(nwg/8) + bid/8
    const int bid = blockIdx.y * gridDim.x + blockIdx.x;
    const int cpx = (gridDim.x * gridDim.y) >> 3;
    const int swzid = (bid & 7) * cpx + (bid >> 3);
    const int bx = swzid % gridDim.x, by = swzid / gridDim.x;

    const int m0 = bx * 128, n0 = by * 128;
    const int wave = threadIdx.x >> 6, lane = threadIdx.x & 63;
    const int quad = lane >> 4, mm = lane & 15;
    const int wm = (wave >> 1) * 64, wn = (wave & 1) * 64;

    const int srow = wave * 16 + (lane >> 2);
    const int scol = 8 * ((lane & 3) ^ ((lane >> 3) & 3));  // XOR chunk swizzle

    const u16* ag0 = A + (size_t)(m0 + srow) * K + scol;
    const u16* ag1 = A + (size_t)(m0 + 64 + srow) * K + scol;
    const u16* bg0 = Bt + (size_t)(n0 + srow) * K + scol;
    const u16* bg1 = Bt + (size_t)(n0 + 64 + srow) * K + scol;
    const int soff = wave * 512 + lane * 8;   // linear LDS dest (u16 units)

    f32x4 acc[4][4] = {};
    const int swz = (mm >> 1) & 3;

#define GST(buf)                                                              \
    {                                                                         \
        u16* ad = &As[buf][soff];                                             \
        u16* bd = &Bs[buf][soff];                                             \
        async16(ag0, ad);                                                     \
        async16(ag1, ad + 2048);                                              \
        async16(bg0, bd);                                                     \
        async16(bg1, bd + 2048);                                              \
        ag0 += 32; ag1 += 32; bg0 += 32; bg1 += 32;                           \
    }

    GST(0);
    int cur = 0;

    for (int k0 = 0; k0 < K; k0 += 32) {
        __syncthreads();   // buf[cur] DMA drained (own-wave vmcnt) + all waves
        if (k0 + 32 < K) GST(cur ^ 1);
        const u16* Ac = &As[cur][0];
        const u16* Bc = &Bs[cur][0];
        half8 af[4], bf[4];
#pragma unroll
        for (int i = 0; i < 4; i++)
            af[i] = *(const half8*)(Ac + (wm + i * 16 + mm) * 32 + (quad ^ swz) * 8);
#pragma unroll
        for (int i = 0; i < 4; i++)
            bf[i] = *(const half8*)(Bc + (wn + i * 16 + mm) * 32 + (quad ^ swz) * 8);
#pragma unroll
        for (int mi = 0; mi < 4; mi++)
#pragma unroll
            for (int ni = 0; ni < 4; ni++)
                acc[mi][ni] = __builtin_amdgcn_mfma_f32_16x16x32_f16(
                    af[mi], bf[ni], acc[mi][ni], 0, 0, 0);
        cur ^= 1;
    }
#undef GST

    if (OUTMODE == 0) {
        float* Cp = (float*)C;
#pragma unroll
        for (int mi = 0; mi < 4; mi++)
#pragma unroll
            for (int r = 0; r < 4; r++) {
                float* rp = Cp + (size_t)(m0 + wm + mi * 16 + quad * 4 + r) * ldc + n0 + wn + mm;
#pragma unroll
                for (int ni = 0; ni < 4; ni++) rp[ni * 16] = acc[mi][ni][r];
            }
    } else if (OUTMODE == 1) {
        u16* Cp = (u16*)C;
#pragma unroll
        for (int mi = 0; mi < 4; mi++)
#pragma unroll
            for (int r = 0; r < 4; r++) {
                u16* rp = Cp + (size_t)(m0 + wm + mi * 16 + quad * 4 + r) * ldc + n0 + wn + mm;
#pragma unroll
                for (int ni = 0; ni < 4; ni++) rp[ni * 16] = f2h(acc[mi][ni][r]);
            }
    } else if (OUTMODE == 2) {
        u16* Cp = (u16*)C;
#pragma unroll
        for (int mi = 0; mi < 4; mi++)
#pragma unroll
            for (int ni = 0; ni < 4; ni++) {
                int col = n0 + wn + ni * 16 + mm;
                int row0 = m0 + wm + mi * 16 + quad * 4;
                u16x4 o = { f2h(acc[mi][ni][0]), f2h(acc[mi][ni][1]),
                            f2h(acc[mi][ni][2]), f2h(acc[mi][ni][3]) };
                *(u16x4*)((u16*)Cp + (size_t)col * ldc + row0) = o;
            }
    } else {  // fused QKV
        if (n0 < 2048) {
            u16* Qp = (u16*)C;    // Qb, ldc 2048
#pragma unroll
            for (int mi = 0; mi < 4; mi++)
#pragma unroll
                for (int r = 0; r < 4; r++) {
                    u16* rp = Qp + (size_t)(m0 + wm + mi * 16 + quad * 4 + r) * 2048 + n0 + wn + mm;
#pragma unroll
                    for (int ni = 0; ni < 4; ni++) rp[ni * 16] = f2h(acc[mi][ni][r]);
                }
        } else if (n0 < 2560) {
            u16* Kp = (u16*)C2;   // Kb, ldc 512
#pragma unroll
            for (int mi = 0; mi < 4; mi++)
#pragma unroll
                for (int r = 0; r < 4; r++) {
                    u16* rp = Kp + (size_t)(m0 + wm + mi * 16 + quad * 4 + r) * 512 + (n0 - 2048) + wn + mm;
#pragma unroll
                    for (int ni = 0; ni < 4; ni++) rp[ni * 16] = f2h(acc[mi][ni][r]);
                }
        } else {
            // Vtb, ldc 4096, transposed: one u16x4 store per (mi,ni)
            u16* Vp = (u16*)C2 + (size_t)4096 * 512;
#pragma unroll
            for (int mi = 0; mi < 4; mi++)
#pragma unroll
                for (int ni = 0; ni < 4; ni++) {
                    int col = n0 - 2560 + wn + ni * 16 + mm;
                    int row0 = m0 + wm + mi * 16 + quad * 4;
                    u16x4 o = { f2h(acc[mi][ni][0]), f2h(acc[mi][ni][1]),
                                f2h(acc[mi][ni][2]), f2h(acc[mi][ni][3]) };
                    *(u16x4*)(Vp + (size_t)col * 4096 + row0) = o;
                }
        }
    }
}

// ---------------- flash attention v13: full occupancy ----------------
// Key fact missed for 5 rounds: VGPR_Count has been exactly 64 -- the cap
// for 8 waves/SIMD. v10's spill was a forced 102-cap on a heavier kernel;
// THIS kernel naturally fits full occupancy. v13: 8-wave blocks (512 thr),
// SPLIT=2 -> grid (8,32,4) = 1024 blocks = 4 blocks/CU = 32 waves/CU (2x
// the TLP of every prior round). launch_bounds(512,8): VGPR cap 64 = what
// we already use. LDS 4 x 32KB = 128 <= 160 KB. Cost: fp32 Of round-trip +
// combine (~14us), correctness-verified in R0/v10.
// Fixed-max softmax (C-init -10, log2 domain). Qb pre-scaled by 0.125*log2e.

template <int SPLIT>
__global__ __launch_bounds__(512, 8) void attn_fwd(const u16* __restrict__ Qb,
                                                   const u16* __restrict__ Kb,
                                                   const u16* __restrict__ Vtb,
                                                   u16* __restrict__ Ob,
                                                   float* __restrict__ Of0,
                                                   float* __restrict__ Of1,
                                                   float* __restrict__ Lf) {
    __shared__ __align__(16) u16 Ks[2][64 * 64];   // [buf][key][dim] swizzled
    __shared__ __align__(16) u16 Vs[2][64 * 64];   // [buf][dim][key] swizzled

    const int qtb = blockIdx.x, head = blockIdx.y;
    const int b = blockIdx.z & 1, sp = blockIdx.z >> 1;
    const int kvh = head >> 2;
    const int wave = threadIdx.x >> 6, lane = threadIdx.x & 63;
    const int h = lane >> 5;          // lane half
    const int q32 = lane & 31;        // query within wave tile
    const int t = threadIdx.x;

    const size_t qrow0 = (size_t)b * 2048 + qtb * 256 + wave * 32;
    const int s_beg = sp * (2048 / SPLIT), s_end = s_beg + 2048 / SPLIT;

    // Q fragments (B-operand: col = q32, k = s*16 + h*8 + j), whole kernel
    half8 qf[4];
#pragma unroll
    for (int s = 0; s < 4; s++)
        qf[s] = *(const half8*)(Qb + (qrow0 + q32) * 2048 + head * 64 + s * 16 + h * 8);

    f32x16 accO[2] = {};
    float lpq[4] = {0.f, 0.f, 0.f, 0.f};

    f32x16 NEG10;
#pragma unroll
    for (int i = 0; i < 16; i++) NEG10[i] = -10.f;

    // staging: 512 threads cover the full 64x64 tile: thread t -> LDS bytes
    // t*16, i.e. row t>>3, physical chunk t&7. Source pre-swizzled:
    // logical chunk (t&7)^((t>>3)&7). ONE async16 each for K and V.
    const int srow = t >> 3;
    const int lch = (t & 7) ^ (srow & 7);
    const u16* kg = Kb + ((size_t)b * 2048 + srow) * 512 + kvh * 64 + lch * 8;
    const u16* vg = Vtb + ((size_t)kvh * 64 + srow) * 4096 + b * 2048 + lch * 8;

#define STAGE(buf, s0)                                                        \
    {                                                                         \
        async16(kg + (size_t)(s0) * 512, &Ks[buf][t * 8]);                    \
        async16(vg + (s0), &Vs[buf][t * 8]);                                  \
    }

    int cur = 0;
    STAGE(0, s_beg);

    const int r0 = q32, r1 = 32 + q32;
    const int sw0 = (r0 & 7), sw1 = (r1 & 7);

    for (int s0 = s_beg; s0 < s_end; s0 += 64) {
        __syncthreads();   // drains vmcnt (DMA done) + barrier (readers done)
        int sn = s0 + 64;
        if (sn < s_end) STAGE(cur ^ 1, sn);

        const u16* Kc = &Ks[cur][0];
        const u16* Vc = &Vs[cur][0];
        const u16* Kr0 = Kc + r0 * 64;
        const u16* Kr1 = Kc + r1 * 64;

        // ---- S^T = K Q^T, both 32-key halves, interleaved chains ----
        // s=0 peeled: C operand = NEG10 constant (no accumulator init movs)
        f32x16 a0, a1;
        __builtin_amdgcn_s_setprio(1);
        {
            half8 k0 = *(const half8*)(Kr0 + ((h ^ sw0) << 3));
            a0 = __builtin_amdgcn_mfma_f32_32x32x16_f16(k0, qf[0], NEG10, 0, 0, 0);
            half8 k1 = *(const half8*)(Kr1 + ((h ^ sw1) << 3));
            a1 = __builtin_amdgcn_mfma_f32_32x32x16_f16(k1, qf[0], NEG10, 0, 0, 0);
        }
#pragma unroll
        for (int s = 1; s < 4; s++) {
            half8 k0 = *(const half8*)(Kr0 + (((2 * s + h) ^ sw0) << 3));
            a0 = __builtin_amdgcn_mfma_f32_32x32x16_f16(k0, qf[s], a0, 0, 0, 0);
            half8 k1 = *(const half8*)(Kr1 + (((2 * s + h) ^ sw1) << 3));
            a1 = __builtin_amdgcn_mfma_f32_32x32x16_f16(k1, qf[s], a1, 0, 0, 0);
        }
        __builtin_amdgcn_s_setprio(0);

        // ---- softmax half 0: p = 2^S, pack f16 pairs ----
        u32 w0[8];
#pragma unroll
        for (int m = 0; m < 8; m++) {
            w0[m] = pk2h(fexp2(a0[2 * m]), fexp2(a0[2 * m + 1]));
            lpq[m & 3] = dot2acc(w0[m], lpq[m & 3]);
        }

        // ---- PV half 0 (ks = 0,1) ----
        __builtin_amdgcn_s_setprio(1);
#pragma unroll
        for (int k1 = 0; k1 < 2; k1++) {
            const int ks = k1;
            u32 d0 = w0[4 * k1 + 0], d2 = w0[4 * k1 + 2];
            u32 d1 = w0[4 * k1 + 1], d3 = w0[4 * k1 + 3];
            plswap(d0, d2);
            plswap(d1, d3);
            u32x4 pd = { d0, d1, d2, d3 };
            half8 pf = __builtin_bit_cast(half8, pd);
#pragma unroll
            for (int dt = 0; dt < 2; dt++) {
                const int rv = dt * 32 + q32;
                half8 vf = *(const half8*)(&Vc[rv * 64 + (((2 * ks + h) ^ (rv & 7)) << 3)]);
                accO[dt] = __builtin_amdgcn_mfma_f32_32x32x16_f16(vf, pf, accO[dt], 0, 0, 0);
            }
        }
        __builtin_amdgcn_s_setprio(0);

        // ---- softmax half 1 (independent of PV0 -> runs in its shadow) ----
        u32 w1[8];
#pragma unroll
        for (int m = 0; m < 8; m++) {
            w1[m] = pk2h(fexp2(a1[2 * m]), fexp2(a1[2 * m + 1]));
            lpq[m & 3] = dot2acc(w1[m], lpq[m & 3]);
        }

        // ---- PV half 1 (ks = 2,3) ----
        __builtin_amdgcn_s_setprio(1);
#pragma unroll
        for (int k1 = 0; k1 < 2; k1++) {
            const int ks = 2 + k1;
            u32 d0 = w1[4 * k1 + 0], d2 = w1[4 * k1 + 2];
            u32 d1 = w1[4 * k1 + 1], d3 = w1[4 * k1 + 3];
            plswap(d0, d2);
            plswap(d1, d3);
            u32x4 pd = { d0, d1, d2, d3 };
            half8 pf = __builtin_bit_cast(half8, pd);
#pragma unroll
            for (int dt = 0; dt < 2; dt++) {
                const int rv = dt * 32 + q32;
                half8 vf = *(const half8*)(&Vc[rv * 64 + (((2 * ks + h) ^ (rv & 7)) << 3)]);
                accO[dt] = __builtin_amdgcn_mfma_f32_32x32x16_f16(vf, pf, accO[dt], 0, 0, 0);
            }
        }
        __builtin_amdgcn_s_setprio(0);

        cur ^= 1;
    }
#undef STAGE

    // l: lane holds one half of the keys; pair lane^32 holds the other
    float l = (lpq[0] + lpq[1]) + (lpq[2] + lpq[3]);
    l += __shfl_xor(l, 32);

    const size_t token = qrow0 + q32;
    if (SPLIT == 1) {
        float inv = 1.f / l;
#pragma unroll
        for (int dt = 0; dt < 2; dt++)
#pragma unroll
            for (int rq = 0; rq < 4; rq++) {
                u16x4 o = { f2h(accO[dt][4 * rq + 0] * inv), f2h(accO[dt][4 * rq + 1] * inv),
                            f2h(accO[dt][4 * rq + 2] * inv), f2h(accO[dt][4 * rq + 3] * inv) };
                *(u16x4*)(Ob + token * 2048 + head * 64 + dt * 32 + rq * 8 + h * 4) = o;
            }
    } else {
        float* Op = sp ? Of1 : Of0;
#pragma unroll
        for (int dt = 0; dt < 2; dt++)
#pragma unroll
            for (int rq = 0; rq < 4; rq++) {
                f32x4 o = { accO[dt][4 * rq + 0], accO[dt][4 * rq + 1],
                            accO[dt][4 * rq + 2], accO[dt][4 * rq + 3] };
                *(f32x4*)(Op + token * 2048 + head * 64 + dt * 32 + rq * 8 + h * 4) = o;
            }
        if (!h) Lf[((size_t)sp * 4096 + token) * 32 + head] = l;
    }
}

// combine: Ob = (Of0 + Of1) / (l0 + l1), fp16 out
__global__ void attn_combine(const float* __restrict__ Of0, const float* __restrict__ Of1,
                             const float* __restrict__ Lf, u16* __restrict__ Ob) {
    size_t idx = (size_t)blockIdx.x * 256 + threadIdx.x;
    size_t token = idx >> 9;
    int dq = (int)(idx & 511) * 4;
    int head = dq >> 6;
    float inv = 1.f / (Lf[token * 32 + head] + Lf[(4096 + token) * 32 + head]);
    float4 a = *(const float4*)(Of0 + token * 2048 + dq);
    float4 c = *(const float4*)(Of1 + token * 2048 + dq);
    u16x4 o = { f2h((a.x + c.x) * inv), f2h((a.y + c.y) * inv),
                f2h((a.z + c.z) * inv), f2h((a.w + c.w) * inv) };
    *(u16x4*)(Ob + token * 2048 + dq) = o;
}

// ---------------- launch ----------------

extern "C" void kernel_launch(void* const* d_in, const int* in_sizes, int n_in,
                              void* d_out, int out_size, void* d_ws, size_t ws_size,
                              hipStream_t stream) {
    (void)in_sizes; (void)n_in; (void)out_size;
    const float* x  = (const float*)d_in[0];
    const float* Wq = (const float*)d_in[1];
    const float* Wk = (const float*)d_in[2];
    const float* Wv = (const float*)d_in[3];
    const float* Wo = (const float*)d_in[4];
    float* out = (float*)d_out;

    u16* ws = (u16*)d_ws;
    u16* xb   = ws;                              // [4096][2048]
    u16* Wqt  = xb   + (size_t)4096 * 2048;      // [2048][2048]  \ contiguous 3072-row
    u16* Wkvt = Wqt  + (size_t)2048 * 2048;      // [1024][2048]  / B^T for fused QKV
    u16* Wot  = Wkvt + (size_t)1024 * 2048;      // [2048][2048]
    u16* Qb   = Wot  + (size_t)2048 * 2048;      // [4096][2048]
    u16* Kb   = Qb   + (size_t)4096 * 2048;      // [4096][512]
    u16* Vtb  = Kb   + (size_t)4096 * 512;       // [512][4096] (= Kb + 4096*512, OUTMODE 3)
    u16* Ob   = Vtb  + (size_t)512 * 4096;       // [4096][2048]
    u16* wend = Ob   + (size_t)4096 * 2048;
    float* Of1 = (float*)wend;                            // 33.5 MB
    float* Lf  = (float*)((char*)Of1 + (size_t)4096 * 2048 * 4);  // 1 MB
    size_t need = (size_t)((char*)Lf - (char*)d_ws) + (size_t)2 * 4096 * 32 * 4;
    const bool split = ws_size >= need;

    // fold softmax scale (1/8) and log2(e) into Wq
    const float qscale = 0.125f * 1.4426950408889634f;

    // fused prologue: x cast + 4 weight transposes, one dispatch
    prep_inputs<<<dim3(64, 64, 5), 256, 0, stream>>>(x, xb, Wq, Wk, Wv, Wo,
                                                     Wqt, Wkvt, Wot, qscale);

    // fused QKV projection: N = 2048 (Q) + 512 (K) + 512 (V) = 3072
    gemm_bt<3><<<dim3(32, 24), 256, 0, stream>>>(xb, Wqt, Qb, Kb, 4096, 3072, 2048, 2048);

    if (split) {
        attn_fwd<2><<<dim3(8, 32, 4), 512, 0, stream>>>(Qb, Kb, Vtb, Ob, out, Of1, Lf);
        attn_combine<<<8192, 256, 0, stream>>>(out, Of1, Lf, Ob);
    } else {
        attn_fwd<1><<<dim3(8, 32, 2), 512, 0, stream>>>(Qb, Kb, Vtb, Ob,
                                                        nullptr, nullptr, nullptr);
    }

    gemm_bt<0><<<dim3(32, 16), 256, 0, stream>>>(Ob, Wot, out, nullptr, 4096, 2048, 2048, 2048);
}

// Round 10
// 315.298 us; speedup vs baseline: 2.6873x; 2.6873x over previous
//
#include <hip/hip_runtime.h>

#define AS1 __attribute__((address_space(1)))
#define AS3 __attribute__((address_space(3)))

typedef unsigned short u16;
typedef unsigned int u32;
typedef __attribute__((ext_vector_type(8))) _Float16 half8;
typedef __attribute__((ext_vector_type(2))) _Float16 half2v;
typedef __attribute__((ext_vector_type(4))) u16 u16x4;
typedef __attribute__((ext_vector_type(8))) u16 u16x8;
typedef __attribute__((ext_vector_type(4))) u32 u32x4;
typedef __attribute__((ext_vector_type(4))) float f32x4;
typedef __attribute__((ext_vector_type(16))) float f32x16;

__device__ __forceinline__ u16 f2h(float f) {
    _Float16 h = (_Float16)f;
    return __builtin_bit_cast(u16, h);
}

__device__ __forceinline__ u32 pk2h(float a, float b) {
    return __builtin_bit_cast(u32, __builtin_amdgcn_cvt_pkrtz(a, b));
}

__device__ __forceinline__ float fexp2(float x) {
#if __has_builtin(__builtin_amdgcn_exp2f)
    return __builtin_amdgcn_exp2f(x);
#else
    return __expf(x * 0.69314718055994531f);
#endif
}

// l += p.lo + p.hi on packed f16 (consistent with the f16 P used by PV)
__device__ __forceinline__ float dot2acc(u32 w, float acc) {
#if __has_builtin(__builtin_amdgcn_fdot2)
    half2v ones = { (_Float16)1.f, (_Float16)1.f };
    return __builtin_amdgcn_fdot2(__builtin_bit_cast(half2v, w), ones, acc, false);
#else
    half2v p = __builtin_bit_cast(half2v, w);
    return acc + (float)p[0] + (float)p[1];
#endif
}

// v_permlane32_swap_b32: a' = [a.lo32, b.lo32], b' = [a.hi32, b.hi32]
__device__ __forceinline__ void plswap(u32& a, u32& b) {
    asm("v_permlane32_swap_b32 %0, %1" : "+v"(a), "+v"(b));
}

// async global->LDS, 16B per lane. LDS dest must be waveBase + lane*16.
__device__ __forceinline__ void async16(const void* g, void* l) {
    __builtin_amdgcn_global_load_lds((AS1 void*)g, (AS3 void*)l, 16, 0, 0);
}

// ---------------- prologue: ONE fused prep dispatch ----------------
// z=0: Wq transpose (scaled), z=1: Wo transpose, z=2: Wk, z=3: Wv,
// z=4: x cast (4096 blocks x 256 thr x 8 elems).

__global__ void prep_inputs(const float* __restrict__ x, u16* __restrict__ xb,
                            const float* __restrict__ Wq, const float* __restrict__ Wk,
                            const float* __restrict__ Wv, const float* __restrict__ Wo,
                            u16* __restrict__ Wqt, u16* __restrict__ Wkvt,
                            u16* __restrict__ Wot, float qscale) {
    __shared__ float tile[32][33];
    const int z = blockIdx.z;
    if (z == 4) {
        size_t base = ((size_t)(blockIdx.y * 64 + blockIdx.x) * 256 + threadIdx.x) * 8;
        float4 v0 = *(const float4*)(x + base);
        float4 v1 = *(const float4*)(x + base + 4);
        u16x8 o = { f2h(v0.x), f2h(v0.y), f2h(v0.z), f2h(v0.w),
                    f2h(v1.x), f2h(v1.y), f2h(v1.z), f2h(v1.w) };
        *(u16x8*)(xb + base) = o;
        return;
    }
    const float* in;
    u16* out;
    int N;
    float scale = 1.f;
    if (z == 0)      { in = Wq; out = Wqt; N = 2048; scale = qscale; }
    else if (z == 1) { in = Wo; out = Wot; N = 2048; }
    else if (z == 2) { in = Wk; out = Wkvt; N = 512; }
    else             { in = Wv; out = Wkvt + (size_t)512 * 2048; N = 512; }
    const int K = 2048;
    int nb = blockIdx.x * 32, kb = blockIdx.y * 32;
    if (nb >= N) return;
    int tx = threadIdx.x & 31, ty = threadIdx.x >> 5;   // 32 x 8
#pragma unroll
    for (int r = ty; r < 32; r += 8)
        tile[r][tx] = in[(size_t)(kb + r) * N + nb + tx];
    __syncthreads();
#pragma unroll
    for (int r = ty; r < 32; r += 8)
        out[(size_t)(nb + r) * K + kb + tx] = f2h(tile[tx][r] * scale);
}

// ---------------- GEMM: C[M,N] = A[M,K] * Bt[N,K]^T ----------------
// v3: 3-buffer, 2-deep global_load_lds prefetch with COUNTED vmcnt (T3/T4).
// The old __syncthreads drained vmcnt(0) -- including the just-issued
// next-tile DMA -- exposing full load latency (L2 ~200 / HBM ~900 cyc)
// against ~350 cyc of compute, 64x per block. Now: each wave issues exactly
// 4 DMAs per stage (FIFO), so s_waitcnt vmcnt(4) at iter k guarantees tile
// k's writes landed for EVERY wave before any wave crosses the raw
// s_barrier; tile k+1's 4 loads stay in flight across it. Buffer (k+2)%3
// overwritten at iter k was last read at iter k-1 (barrier-protected).
// LDS 48 KB/block; (256,2) -> 96 KB/CU, (256,3) -> 144 <= 160 KB.
// XCD-aware bijective block swizzle (T1) kept: nwg 768/512, both %8==0.
// OUTMODE 0 = fp32 out, 1 = fp16 out, 2 = fp16 transposed,
// OUTMODE 3 = fused QKV: n<2048 -> Qb (C, ldc 2048); <2560 -> Kb (C2, ldc
//   512); else Vtb transposed (C2 + 4096*512, ldc 4096).

template <int OUTMODE>
__global__ __launch_bounds__(256, OUTMODE == 3 ? 3 : 2) void gemm_bt(
        const u16* __restrict__ A, const u16* __restrict__ Bt,
        void* __restrict__ C, void* __restrict__ C2,
        int M, int N, int K, int ldc) {
    __shared__ __align__(16) u16 As[3][128 * 32];
    __shared__ __align__(16) u16 Bs[3][128 * 32];
    // XCD swizzle: logical id = (bid%8)*(nwg/8) + bid/8
    const int bid = blockIdx.y * gridDim.x + blockIdx.x;
    const int cpx = (gridDim.x * gridDim.y) >> 3;
    const int swzid = (bid & 7) * cpx + (bid >> 3);
    const int bx = swzid % gridDim.x, by = swzid / gridDim.x;

    const int m0 = bx * 128, n0 = by * 128;
    const int wave = threadIdx.x >> 6, lane = threadIdx.x & 63;
    const int quad = lane >> 4, mm = lane & 15;
    const int wm = (wave >> 1) * 64, wn = (wave & 1) * 64;

    const int srow = wave * 16 + (lane >> 2);
    const int scol = 8 * ((lane & 3) ^ ((lane >> 3) & 3));  // XOR chunk swizzle

    const u16* ag0 = A + (size_t)(m0 + srow) * K + scol;
    const u16* ag1 = A + (size_t)(m0 + 64 + srow) * K + scol;
    const u16* bg0 = Bt + (size_t)(n0 + srow) * K + scol;
    const u16* bg1 = Bt + (size_t)(n0 + 64 + srow) * K + scol;
    const int soff = wave * 512 + lane * 8;   // linear LDS dest (u16 units)

    f32x4 acc[4][4] = {};
    const int swz = (mm >> 1) & 3;

#define GST(buf)                                                              \
    {                                                                         \
        u16* ad = &As[buf][soff];                                             \
        u16* bd = &Bs[buf][soff];                                             \
        async16(ag0, ad);                                                     \
        async16(ag1, ad + 2048);                                              \
        async16(bg0, bd);                                                     \
        async16(bg1, bd + 2048);                                              \
        ag0 += 32; ag1 += 32; bg0 += 32; bg1 += 32;                           \
    }

    GST(0);
    GST(1);
    int cur = 0;

    for (int k0 = 0; k0 < K; k0 += 32) {
        // tile-k DMA complete (4 per stage, FIFO); tile-k+1's 4 stay in flight
        if (k0 + 32 < K) {
            asm volatile("s_waitcnt vmcnt(4)" ::: "memory");
        } else {
            asm volatile("s_waitcnt vmcnt(0)" ::: "memory");
        }
        __builtin_amdgcn_s_barrier();
        if (k0 + 64 < K) {
            int nb = cur + 2;
            if (nb >= 3) nb -= 3;
            GST(nb);
        }
        const u16* Ac = &As[cur][0];
        const u16* Bc = &Bs[cur][0];
        half8 af[4], bf[4];
#pragma unroll
        for (int i = 0; i < 4; i++)
            af[i] = *(const half8*)(Ac + (wm + i * 16 + mm) * 32 + (quad ^ swz) * 8);
#pragma unroll
        for (int i = 0; i < 4; i++)
            bf[i] = *(const half8*)(Bc + (wn + i * 16 + mm) * 32 + (quad ^ swz) * 8);
#pragma unroll
        for (int mi = 0; mi < 4; mi++)
#pragma unroll
            for (int ni = 0; ni < 4; ni++)
                acc[mi][ni] = __builtin_amdgcn_mfma_f32_16x16x32_f16(
                    af[mi], bf[ni], acc[mi][ni], 0, 0, 0);
        if (++cur == 3) cur = 0;
    }
#undef GST

    if (OUTMODE == 0) {
        float* Cp = (float*)C;
#pragma unroll
        for (int mi = 0; mi < 4; mi++)
#pragma unroll
            for (int r = 0; r < 4; r++) {
                float* rp = Cp + (size_t)(m0 + wm + mi * 16 + quad * 4 + r) * ldc + n0 + wn + mm;
#pragma unroll
                for (int ni = 0; ni < 4; ni++) rp[ni * 16] = acc[mi][ni][r];
            }
    } else if (OUTMODE == 1) {
        u16* Cp = (u16*)C;
#pragma unroll
        for (int mi = 0; mi < 4; mi++)
#pragma unroll
            for (int r = 0; r < 4; r++) {
                u16* rp = Cp + (size_t)(m0 + wm + mi * 16 + quad * 4 + r) * ldc + n0 + wn + mm;
#pragma unroll
                for (int ni = 0; ni < 4; ni++) rp[ni * 16] = f2h(acc[mi][ni][r]);
            }
    } else if (OUTMODE == 2) {
        u16* Cp = (u16*)C;
#pragma unroll
        for (int mi = 0; mi < 4; mi++)
#pragma unroll
            for (int ni = 0; ni < 4; ni++) {
                int col = n0 + wn + ni * 16 + mm;
                int row0 = m0 + wm + mi * 16 + quad * 4;
                u16x4 o = { f2h(acc[mi][ni][0]), f2h(acc[mi][ni][1]),
                            f2h(acc[mi][ni][2]), f2h(acc[mi][ni][3]) };
                *(u16x4*)((u16*)Cp + (size_t)col * ldc + row0) = o;
            }
    } else {  // fused QKV
        if (n0 < 2048) {
            u16* Qp = (u16*)C;    // Qb, ldc 2048
#pragma unroll
            for (int mi = 0; mi < 4; mi++)
#pragma unroll
                for (int r = 0; r < 4; r++) {
                    u16* rp = Qp + (size_t)(m0 + wm + mi * 16 + quad * 4 + r) * 2048 + n0 + wn + mm;
#pragma unroll
                    for (int ni = 0; ni < 4; ni++) rp[ni * 16] = f2h(acc[mi][ni][r]);
                }
        } else if (n0 < 2560) {
            u16* Kp = (u16*)C2;   // Kb, ldc 512
#pragma unroll
            for (int mi = 0; mi < 4; mi++)
#pragma unroll
                for (int r = 0; r < 4; r++) {
                    u16* rp = Kp + (size_t)(m0 + wm + mi * 16 + quad * 4 + r) * 512 + (n0 - 2048) + wn + mm;
#pragma unroll
                    for (int ni = 0; ni < 4; ni++) rp[ni * 16] = f2h(acc[mi][ni][r]);
                }
        } else {
            // Vtb, ldc 4096, transposed: one u16x4 store per (mi,ni)
            u16* Vp = (u16*)C2 + (size_t)4096 * 512;
#pragma unroll
            for (int mi = 0; mi < 4; mi++)
#pragma unroll
                for (int ni = 0; ni < 4; ni++) {
                    int col = n0 - 2560 + wn + ni * 16 + mm;
                    int row0 = m0 + wm + mi * 16 + quad * 4;
                    u16x4 o = { f2h(acc[mi][ni][0]), f2h(acc[mi][ni][1]),
                                f2h(acc[mi][ni][2]), f2h(acc[mi][ni][3]) };
                    *(u16x4*)(Vp + (size_t)col * 4096 + row0) = o;
                }
        }
    }
}

// ---------------- flash attention v12 (reverted, known-good 88us) --------
// R9 post-mortem: CSV VGPR_Count=64 is ARCH VGPRs only; accO/accST live in
// AGPRs (unified file) -> true footprint ~128 regs. (512,8) halved the
// budget to 64 -> VGPR_Count 32 + 2.8 GB spill, 589us. Occupancy axis
// CLOSED at 16 waves/CU (4 waves/SIMD, 128 unified regs). This is v12
// exactly: 8-wave blocks, (512,4), SPLIT=1.
// Fixed-max softmax (C-init -10, log2 domain). Qb pre-scaled by 0.125*log2e.

template <int SPLIT>
__global__ __launch_bounds__(512, 4) void attn_fwd(const u16* __restrict__ Qb,
                                                   const u16* __restrict__ Kb,
                                                   const u16* __restrict__ Vtb,
                                                   u16* __restrict__ Ob,
                                                   float* __restrict__ Of0,
                                                   float* __restrict__ Of1,
                                                   float* __restrict__ Lf) {
    __shared__ __align__(16) u16 Ks[2][64 * 64];   // [buf][key][dim] swizzled
    __shared__ __align__(16) u16 Vs[2][64 * 64];   // [buf][dim][key] swizzled

    const int qtb = blockIdx.x, head = blockIdx.y;
    const int b = blockIdx.z & 1, sp = blockIdx.z >> 1;
    const int kvh = head >> 2;
    const int wave = threadIdx.x >> 6, lane = threadIdx.x & 63;
    const int h = lane >> 5;          // lane half
    const int q32 = lane & 31;        // query within wave tile
    const int t = threadIdx.x;

    const size_t qrow0 = (size_t)b * 2048 + qtb * 256 + wave * 32;
    const int s_beg = sp * (2048 / SPLIT), s_end = s_beg + 2048 / SPLIT;

    // Q fragments (B-operand: col = q32, k = s*16 + h*8 + j), whole kernel
    half8 qf[4];
#pragma unroll
    for (int s = 0; s < 4; s++)
        qf[s] = *(const half8*)(Qb + (qrow0 + q32) * 2048 + head * 64 + s * 16 + h * 8);

    f32x16 accO[2] = {};
    float lpq[4] = {0.f, 0.f, 0.f, 0.f};

    f32x16 NEG10;
#pragma unroll
    for (int i = 0; i < 16; i++) NEG10[i] = -10.f;

    // staging: 512 threads cover the full 64x64 tile: thread t -> LDS bytes
    // t*16, i.e. row t>>3, physical chunk t&7. Source pre-swizzled:
    // logical chunk (t&7)^((t>>3)&7). ONE async16 each for K and V.
    const int srow = t >> 3;
    const int lch = (t & 7) ^ (srow & 7);
    const u16* kg = Kb + ((size_t)b * 2048 + srow) * 512 + kvh * 64 + lch * 8;
    const u16* vg = Vtb + ((size_t)kvh * 64 + srow) * 4096 + b * 2048 + lch * 8;

#define STAGE(buf, s0)                                                        \
    {                                                                         \
        async16(kg + (size_t)(s0) * 512, &Ks[buf][t * 8]);                    \
        async16(vg + (s0), &Vs[buf][t * 8]);                                  \
    }

    int cur = 0;
    STAGE(0, s_beg);

    const int r0 = q32, r1 = 32 + q32;
    const int sw0 = (r0 & 7), sw1 = (r1 & 7);

    for (int s0 = s_beg; s0 < s_end; s0 += 64) {
        __syncthreads();   // drains vmcnt (DMA done) + barrier (readers done)
        int sn = s0 + 64;
        if (sn < s_end) STAGE(cur ^ 1, sn);

        const u16* Kc = &Ks[cur][0];
        const u16* Vc = &Vs[cur][0];
        const u16* Kr0 = Kc + r0 * 64;
        const u16* Kr1 = Kc + r1 * 64;

        // ---- S^T = K Q^T, both 32-key halves, interleaved chains ----
        // s=0 peeled: C operand = NEG10 constant (no accumulator init movs)
        f32x16 a0, a1;
        __builtin_amdgcn_s_setprio(1);
        {
            half8 k0 = *(const half8*)(Kr0 + ((h ^ sw0) << 3));
            a0 = __builtin_amdgcn_mfma_f32_32x32x16_f16(k0, qf[0], NEG10, 0, 0, 0);
            half8 k1 = *(const half8*)(Kr1 + ((h ^ sw1) << 3));
            a1 = __builtin_amdgcn_mfma_f32_32x32x16_f16(k1, qf[0], NEG10, 0, 0, 0);
        }
#pragma unroll
        for (int s = 1; s < 4; s++) {
            half8 k0 = *(const half8*)(Kr0 + (((2 * s + h) ^ sw0) << 3));
            a0 = __builtin_amdgcn_mfma_f32_32x32x16_f16(k0, qf[s], a0, 0, 0, 0);
            half8 k1 = *(const half8*)(Kr1 + (((2 * s + h) ^ sw1) << 3));
            a1 = __builtin_amdgcn_mfma_f32_32x32x16_f16(k1, qf[s], a1, 0, 0, 0);
        }
        __builtin_amdgcn_s_setprio(0);

        // ---- softmax half 0: p = 2^S, pack f16 pairs ----
        u32 w0[8];
#pragma unroll
        for (int m = 0; m < 8; m++) {
            w0[m] = pk2h(fexp2(a0[2 * m]), fexp2(a0[2 * m + 1]));
            lpq[m & 3] = dot2acc(w0[m], lpq[m & 3]);
        }

        // ---- PV half 0 (ks = 0,1) ----
        __builtin_amdgcn_s_setprio(1);
#pragma unroll
        for (int k1 = 0; k1 < 2; k1++) {
            const int ks = k1;
            u32 d0 = w0[4 * k1 + 0], d2 = w0[4 * k1 + 2];
            u32 d1 = w0[4 * k1 + 1], d3 = w0[4 * k1 + 3];
            plswap(d0, d2);
            plswap(d1, d3);
            u32x4 pd = { d0, d1, d2, d3 };
            half8 pf = __builtin_bit_cast(half8, pd);
#pragma unroll
            for (int dt = 0; dt < 2; dt++) {
                const int rv = dt * 32 + q32;
                half8 vf = *(const half8*)(&Vc[rv * 64 + (((2 * ks + h) ^ (rv & 7)) << 3)]);
                accO[dt] = __builtin_amdgcn_mfma_f32_32x32x16_f16(vf, pf, accO[dt], 0, 0, 0);
            }
        }
        __builtin_amdgcn_s_setprio(0);

        // ---- softmax half 1 (independent of PV0 -> runs in its shadow) ----
        u32 w1[8];
#pragma unroll
        for (int m = 0; m < 8; m++) {
            w1[m] = pk2h(fexp2(a1[2 * m]), fexp2(a1[2 * m + 1]));
            lpq[m & 3] = dot2acc(w1[m], lpq[m & 3]);
        }

        // ---- PV half 1 (ks = 2,3) ----
        __builtin_amdgcn_s_setprio(1);
#pragma unroll
        for (int k1 = 0; k1 < 2; k1++) {
            const int ks = 2 + k1;
            u32 d0 = w1[4 * k1 + 0], d2 = w1[4 * k1 + 2];
            u32 d1 = w1[4 * k1 + 1], d3 = w1[4 * k1 + 3];
            plswap(d0, d2);
            plswap(d1, d3);
            u32x4 pd = { d0, d1, d2, d3 };
            half8 pf = __builtin_bit_cast(half8, pd);
#pragma unroll
            for (int dt = 0; dt < 2; dt++) {
                const int rv = dt * 32 + q32;
                half8 vf = *(const half8*)(&Vc[rv * 64 + (((2 * ks + h) ^ (rv & 7)) << 3)]);
                accO[dt] = __builtin_amdgcn_mfma_f32_32x32x16_f16(vf, pf, accO[dt], 0, 0, 0);
            }
        }
        __builtin_amdgcn_s_setprio(0);

        cur ^= 1;
    }
#undef STAGE

    // l: lane holds one half of the keys; pair lane^32 holds the other
    float l = (lpq[0] + lpq[1]) + (lpq[2] + lpq[3]);
    l += __shfl_xor(l, 32);

    const size_t token = qrow0 + q32;
    if (SPLIT == 1) {
        float inv = 1.f / l;
#pragma unroll
        for (int dt = 0; dt < 2; dt++)
#pragma unroll
            for (int rq = 0; rq < 4; rq++) {
                u16x4 o = { f2h(accO[dt][4 * rq + 0] * inv), f2h(accO[dt][4 * rq + 1] * inv),
                            f2h(accO[dt][4 * rq + 2] * inv), f2h(accO[dt][4 * rq + 3] * inv) };
                *(u16x4*)(Ob + token * 2048 + head * 64 + dt * 32 + rq * 8 + h * 4) = o;
            }
    } else {
        float* Op = sp ? Of1 : Of0;
#pragma unroll
        for (int dt = 0; dt < 2; dt++)
#pragma unroll
            for (int rq = 0; rq < 4; rq++) {
                f32x4 o = { accO[dt][4 * rq + 0], accO[dt][4 * rq + 1],
                            accO[dt][4 * rq + 2], accO[dt][4 * rq + 3] };
                *(f32x4*)(Op + token * 2048 + head * 64 + dt * 32 + rq * 8 + h * 4) = o;
            }
        if (!h) Lf[((size_t)sp * 4096 + token) * 32 + head] = l;
    }
}

// ---------------- launch ----------------

extern "C" void kernel_launch(void* const* d_in, const int* in_sizes, int n_in,
                              void* d_out, int out_size, void* d_ws, size_t ws_size,
                              hipStream_t stream) {
    (void)in_sizes; (void)n_in; (void)out_size; (void)ws_size;
    const float* x  = (const float*)d_in[0];
    const float* Wq = (const float*)d_in[1];
    const float* Wk = (const float*)d_in[2];
    const float* Wv = (const float*)d_in[3];
    const float* Wo = (const float*)d_in[4];
    float* out = (float*)d_out;

    u16* ws = (u16*)d_ws;
    u16* xb   = ws;                              // [4096][2048]
    u16* Wqt  = xb   + (size_t)4096 * 2048;      // [2048][2048]  \ contiguous 3072-row
    u16* Wkvt = Wqt  + (size_t)2048 * 2048;      // [1024][2048]  / B^T for fused QKV
    u16* Wot  = Wkvt + (size_t)1024 * 2048;      // [2048][2048]
    u16* Qb   = Wot  + (size_t)2048 * 2048;      // [4096][2048]
    u16* Kb   = Qb   + (size_t)4096 * 2048;      // [4096][512]
    u16* Vtb  = Kb   + (size_t)4096 * 512;       // [512][4096] (= Kb + 4096*512, OUTMODE 3)
    u16* Ob   = Vtb  + (size_t)512 * 4096;       // [4096][2048]

    // fold softmax scale (1/8) and log2(e) into Wq
    const float qscale = 0.125f * 1.4426950408889634f;

    // fused prologue: x cast + 4 weight transposes, one dispatch
    prep_inputs<<<dim3(64, 64, 5), 256, 0, stream>>>(x, xb, Wq, Wk, Wv, Wo,
                                                     Wqt, Wkvt, Wot, qscale);

    // fused QKV projection: N = 2048 (Q) + 512 (K) + 512 (V) = 3072
    gemm_bt<3><<<dim3(32, 24), 256, 0, stream>>>(xb, Wqt, Qb, Kb, 4096, 3072, 2048, 2048);

    attn_fwd<1><<<dim3(8, 32, 2), 512, 0, stream>>>(Qb, Kb, Vtb, Ob,
                                                    nullptr, nullptr, nullptr);

    gemm_bt<0><<<dim3(32, 16), 256, 0, stream>>>(Ob, Wot, out, nullptr, 4096, 2048, 2048, 2048);
}

// Round 11
// 296.562 us; speedup vs baseline: 2.8570x; 1.0632x over previous
//
#include <hip/hip_runtime.h>

#define AS1 __attribute__((address_space(1)))
#define AS3 __attribute__((address_space(3)))

typedef unsigned short u16;
typedef unsigned int u32;
typedef __attribute__((ext_vector_type(8))) _Float16 half8;
typedef __attribute__((ext_vector_type(2))) _Float16 half2v;
typedef __attribute__((ext_vector_type(4))) u16 u16x4;
typedef __attribute__((ext_vector_type(8))) u16 u16x8;
typedef __attribute__((ext_vector_type(4))) u32 u32x4;
typedef __attribute__((ext_vector_type(4))) float f32x4;
typedef __attribute__((ext_vector_type(16))) float f32x16;

__device__ __forceinline__ u16 f2h(float f) {
    _Float16 h = (_Float16)f;
    return __builtin_bit_cast(u16, h);
}

__device__ __forceinline__ u32 pk2h(float a, float b) {
    return __builtin_bit_cast(u32, __builtin_amdgcn_cvt_pkrtz(a, b));
}

__device__ __forceinline__ float fexp2(float x) {
#if __has_builtin(__builtin_amdgcn_exp2f)
    return __builtin_amdgcn_exp2f(x);
#else
    return __expf(x * 0.69314718055994531f);
#endif
}

// l += p.lo + p.hi on packed f16 (consistent with the f16 P used by PV)
__device__ __forceinline__ float dot2acc(u32 w, float acc) {
#if __has_builtin(__builtin_amdgcn_fdot2)
    half2v ones = { (_Float16)1.f, (_Float16)1.f };
    return __builtin_amdgcn_fdot2(__builtin_bit_cast(half2v, w), ones, acc, false);
#else
    half2v p = __builtin_bit_cast(half2v, w);
    return acc + (float)p[0] + (float)p[1];
#endif
}

// v_permlane32_swap_b32: a' = [a.lo32, b.lo32], b' = [a.hi32, b.hi32]
__device__ __forceinline__ void plswap(u32& a, u32& b) {
    asm("v_permlane32_swap_b32 %0, %1" : "+v"(a), "+v"(b));
}

// async global->LDS, 16B per lane. LDS dest must be waveBase + lane*16.
__device__ __forceinline__ void async16(const void* g, void* l) {
    __builtin_amdgcn_global_load_lds((AS1 void*)g, (AS3 void*)l, 16, 0, 0);
}

// ---------------- prologue: ONE fused prep dispatch ----------------
// z=0: Wq transpose (scaled), z=1: Wo transpose, z=2: Wk, z=3: Wv,
// z=4: x cast. Transpose fp32 reads vectorized as float4 (8x32 thread map).

__global__ void prep_inputs(const float* __restrict__ x, u16* __restrict__ xb,
                            const float* __restrict__ Wq, const float* __restrict__ Wk,
                            const float* __restrict__ Wv, const float* __restrict__ Wo,
                            u16* __restrict__ Wqt, u16* __restrict__ Wkvt,
                            u16* __restrict__ Wot, float qscale) {
    __shared__ float tile[32][33];
    const int z = blockIdx.z;
    if (z == 4) {
        size_t base = ((size_t)(blockIdx.y * 64 + blockIdx.x) * 256 + threadIdx.x) * 8;
        float4 v0 = *(const float4*)(x + base);
        float4 v1 = *(const float4*)(x + base + 4);
        u16x8 o = { f2h(v0.x), f2h(v0.y), f2h(v0.z), f2h(v0.w),
                    f2h(v1.x), f2h(v1.y), f2h(v1.z), f2h(v1.w) };
        *(u16x8*)(xb + base) = o;
        return;
    }
    const float* in;
    u16* out;
    int N;
    float scale = 1.f;
    if (z == 0)      { in = Wq; out = Wqt; N = 2048; scale = qscale; }
    else if (z == 1) { in = Wo; out = Wot; N = 2048; }
    else if (z == 2) { in = Wk; out = Wkvt; N = 512; }
    else             { in = Wv; out = Wkvt + (size_t)512 * 2048; N = 512; }
    const int K = 2048;
    int nb = blockIdx.x * 32, kb = blockIdx.y * 32;
    if (nb >= N) return;
    // load: one float4 per thread (8 x 32 map), coalesced 128B per row-octet
    {
        int r = threadIdx.x >> 3, c4 = (threadIdx.x & 7) * 4;
        float4 v = *(const float4*)(in + (size_t)(kb + r) * N + nb + c4);
        tile[r][c4 + 0] = v.x; tile[r][c4 + 1] = v.y;
        tile[r][c4 + 2] = v.z; tile[r][c4 + 3] = v.w;
    }
    __syncthreads();
    int tx = threadIdx.x & 31, ty = threadIdx.x >> 5;   // 32 x 8
#pragma unroll
    for (int r = ty; r < 32; r += 8)
        out[(size_t)(nb + r) * K + kb + tx] = f2h(tile[tx][r] * scale);
}

// ---------------- GEMM: C[M,N] = A[M,K] * Bt[N,K]^T ----------------
// v3 (QKV): 3-buffer, 2-deep global_load_lds prefetch, counted vmcnt, BK=32.
// XCD-aware bijective block swizzle (T1). nwg must be %8==0.
// OUTMODE 3 = fused QKV: n<2048 -> Qb (C, ldc 2048); <2560 -> Kb (C2, ldc
//   512); else Vtb transposed (C2 + 4096*512, ldc 4096).

template <int OUTMODE>
__global__ __launch_bounds__(256, OUTMODE == 3 ? 3 : 2) void gemm_bt(
        const u16* __restrict__ A, const u16* __restrict__ Bt,
        void* __restrict__ C, void* __restrict__ C2,
        int M, int N, int K, int ldc) {
    __shared__ __align__(16) u16 As[3][128 * 32];
    __shared__ __align__(16) u16 Bs[3][128 * 32];
    // XCD swizzle: logical id = (bid%8)*(nwg/8) + bid/8
    const int bid = blockIdx.y * gridDim.x + blockIdx.x;
    const int cpx = (gridDim.x * gridDim.y) >> 3;
    const int swzid = (bid & 7) * cpx + (bid >> 3);
    const int bx = swzid % gridDim.x, by = swzid / gridDim.x;

    const int m0 = bx * 128, n0 = by * 128;
    const int wave = threadIdx.x >> 6, lane = threadIdx.x & 63;
    const int quad = lane >> 4, mm = lane & 15;
    const int wm = (wave >> 1) * 64, wn = (wave & 1) * 64;

    const int srow = wave * 16 + (lane >> 2);
    const int scol = 8 * ((lane & 3) ^ ((lane >> 3) & 3));  // XOR chunk swizzle

    const u16* ag0 = A + (size_t)(m0 + srow) * K + scol;
    const u16* ag1 = A + (size_t)(m0 + 64 + srow) * K + scol;
    const u16* bg0 = Bt + (size_t)(n0 + srow) * K + scol;
    const u16* bg1 = Bt + (size_t)(n0 + 64 + srow) * K + scol;
    const int soff = wave * 512 + lane * 8;   // linear LDS dest (u16 units)

    f32x4 acc[4][4] = {};
    const int swz = (mm >> 1) & 3;

#define GST(buf)                                                              \
    {                                                                         \
        u16* ad = &As[buf][soff];                                             \
        u16* bd = &Bs[buf][soff];                                             \
        async16(ag0, ad);                                                     \
        async16(ag1, ad + 2048);                                              \
        async16(bg0, bd);                                                     \
        async16(bg1, bd + 2048);                                              \
        ag0 += 32; ag1 += 32; bg0 += 32; bg1 += 32;                           \
    }

    GST(0);
    GST(1);
    int cur = 0;

    for (int k0 = 0; k0 < K; k0 += 32) {
        if (k0 + 32 < K) {
            asm volatile("s_waitcnt vmcnt(4)" ::: "memory");
        } else {
            asm volatile("s_waitcnt vmcnt(0)" ::: "memory");
        }
        __builtin_amdgcn_s_barrier();
        if (k0 + 64 < K) {
            int nb = cur + 2;
            if (nb >= 3) nb -= 3;
            GST(nb);
        }
        const u16* Ac = &As[cur][0];
        const u16* Bc = &Bs[cur][0];
        half8 af[4], bf[4];
#pragma unroll
        for (int i = 0; i < 4; i++)
            af[i] = *(const half8*)(Ac + (wm + i * 16 + mm) * 32 + (quad ^ swz) * 8);
#pragma unroll
        for (int i = 0; i < 4; i++)
            bf[i] = *(const half8*)(Bc + (wn + i * 16 + mm) * 32 + (quad ^ swz) * 8);
#pragma unroll
        for (int mi = 0; mi < 4; mi++)
#pragma unroll
            for (int ni = 0; ni < 4; ni++)
                acc[mi][ni] = __builtin_amdgcn_mfma_f32_16x16x32_f16(
                    af[mi], bf[ni], acc[mi][ni], 0, 0, 0);
        if (++cur == 3) cur = 0;
    }
#undef GST

    if (OUTMODE == 0) {
        float* Cp = (float*)C;
#pragma unroll
        for (int mi = 0; mi < 4; mi++)
#pragma unroll
            for (int r = 0; r < 4; r++) {
                float* rp = Cp + (size_t)(m0 + wm + mi * 16 + quad * 4 + r) * ldc + n0 + wn + mm;
#pragma unroll
                for (int ni = 0; ni < 4; ni++) rp[ni * 16] = acc[mi][ni][r];
            }
    } else if (OUTMODE == 1) {
        u16* Cp = (u16*)C;
#pragma unroll
        for (int mi = 0; mi < 4; mi++)
#pragma unroll
            for (int r = 0; r < 4; r++) {
                u16* rp = Cp + (size_t)(m0 + wm + mi * 16 + quad * 4 + r) * ldc + n0 + wn + mm;
#pragma unroll
                for (int ni = 0; ni < 4; ni++) rp[ni * 16] = f2h(acc[mi][ni][r]);
            }
    } else if (OUTMODE == 2) {
        u16* Cp = (u16*)C;
#pragma unroll
        for (int mi = 0; mi < 4; mi++)
#pragma unroll
            for (int ni = 0; ni < 4; ni++) {
                int col = n0 + wn + ni * 16 + mm;
                int row0 = m0 + wm + mi * 16 + quad * 4;
                u16x4 o = { f2h(acc[mi][ni][0]), f2h(acc[mi][ni][1]),
                            f2h(acc[mi][ni][2]), f2h(acc[mi][ni][3]) };
                *(u16x4*)((u16*)Cp + (size_t)col * ldc + row0) = o;
            }
    } else {  // fused QKV
        if (n0 < 2048) {
            u16* Qp = (u16*)C;    // Qb, ldc 2048
#pragma unroll
            for (int mi = 0; mi < 4; mi++)
#pragma unroll
                for (int r = 0; r < 4; r++) {
                    u16* rp = Qp + (size_t)(m0 + wm + mi * 16 + quad * 4 + r) * 2048 + n0 + wn + mm;
#pragma unroll
                    for (int ni = 0; ni < 4; ni++) rp[ni * 16] = f2h(acc[mi][ni][r]);
                }
        } else if (n0 < 2560) {
            u16* Kp = (u16*)C2;   // Kb, ldc 512
#pragma unroll
            for (int mi = 0; mi < 4; mi++)
#pragma unroll
                for (int r = 0; r < 4; r++) {
                    u16* rp = Kp + (size_t)(m0 + wm + mi * 16 + quad * 4 + r) * 512 + (n0 - 2048) + wn + mm;
#pragma unroll
                    for (int ni = 0; ni < 4; ni++) rp[ni * 16] = f2h(acc[mi][ni][r]);
                }
        } else {
            // Vtb, ldc 4096, transposed: one u16x4 store per (mi,ni)
            u16* Vp = (u16*)C2 + (size_t)4096 * 512;
#pragma unroll
            for (int mi = 0; mi < 4; mi++)
#pragma unroll
                for (int ni = 0; ni < 4; ni++) {
                    int col = n0 - 2560 + wn + ni * 16 + mm;
                    int row0 = m0 + wm + mi * 16 + quad * 4;
                    u16x4 o = { f2h(acc[mi][ni][0]), f2h(acc[mi][ni][1]),
                                f2h(acc[mi][ni][2]), f2h(acc[mi][ni][3]) };
                    *(u16x4*)(Vp + (size_t)col * 4096 + row0) = o;
                }
        }
    }
}

// ---------------- Wo GEMM: BK=64 (fp32 out) ----------------
// Wo gemm is grid-capped at 512 blocks = 2/CU -- occupancy can't rise, so
// BK=64 is free here (m132's BK regression was an occupancy drop; none
// possible at 2/CU). Halves barrier-drains (64->32) and doubles MFMA per
// phase (32/wave). LDS 2buf x (16KB A + 16KB B) = 64KB; 2/CU = 128 <= 160.
// Staging involution (rule #21): thread t, row r=(t>>3)+32p, phys slot t&7
// holds logical chunk (t&7)^(r&7) (r&7 == (t>>3)&7, p-invariant); read of
// logical c at row r uses phys c^(r&7). Per-kk fragment loads cap VGPRs.

__global__ __launch_bounds__(256, 2) void gemm_wo(
        const u16* __restrict__ A, const u16* __restrict__ Bt,
        float* __restrict__ C, int M, int N, int K, int ldc) {
    __shared__ __align__(16) u16 As[2][128 * 64];
    __shared__ __align__(16) u16 Bs[2][128 * 64];
    const int bid = blockIdx.y * gridDim.x + blockIdx.x;
    const int cpx = (gridDim.x * gridDim.y) >> 3;
    const int swzid = (bid & 7) * cpx + (bid >> 3);
    const int bx = swzid % gridDim.x, by = swzid / gridDim.x;

    const int m0 = bx * 128, n0 = by * 128;
    const int wave = threadIdx.x >> 6, lane = threadIdx.x & 63;
    const int quad = lane >> 4, mm = lane & 15;
    const int wm = (wave >> 1) * 64, wn = (wave & 1) * 64;
    const int t = threadIdx.x;

    const int srow = t >> 3;                       // rows 0..31 (+32p)
    const int lch = (t & 7) ^ (srow & 7);          // pre-swizzled source chunk
    const u16* ag = A + (size_t)(m0 + srow) * K + lch * 8;
    const u16* bg = Bt + (size_t)(n0 + srow) * K + lch * 8;
    const int d8 = t * 8;                          // dest: row srow, slot t&7

    f32x4 acc[4][4] = {};
    const int swb = mm & 7;

#define GSTW(buf)                                                             \
    {                                                                         \
        _Pragma("unroll")                                                     \
        for (int p = 0; p < 4; p++) {                                         \
            async16(ag + (size_t)(p * 32) * K, &As[buf][d8 + p * 2048]);      \
            async16(bg + (size_t)(p * 32) * K, &Bs[buf][d8 + p * 2048]);      \
        }                                                                     \
        ag += 64; bg += 64;                                                   \
    }

    GSTW(0);
    int cur = 0;

    for (int k0 = 0; k0 < K; k0 += 64) {
        __syncthreads();   // buf[cur] DMA drained (own-wave vmcnt) + all waves
        if (k0 + 64 < K) GSTW(cur ^ 1);
        const u16* Ac = &As[cur][0];
        const u16* Bc = &Bs[cur][0];
#pragma unroll
        for (int kk = 0; kk < 2; kk++) {
            half8 af[4], bf[4];
#pragma unroll
            for (int i = 0; i < 4; i++)
                af[i] = *(const half8*)(Ac + (wm + i * 16 + mm) * 64 +
                                        (((kk * 4 + quad) ^ swb) << 3));
#pragma unroll
            for (int i = 0; i < 4; i++)
                bf[i] = *(const half8*)(Bc + (wn + i * 16 + mm) * 64 +
                                        (((kk * 4 + quad) ^ swb) << 3));
#pragma unroll
            for (int mi = 0; mi < 4; mi++)
#pragma unroll
                for (int ni = 0; ni < 4; ni++)
                    acc[mi][ni] = __builtin_amdgcn_mfma_f32_16x16x32_f16(
                        af[mi], bf[ni], acc[mi][ni], 0, 0, 0);
        }
        cur ^= 1;
    }
#undef GSTW

#pragma unroll
    for (int mi = 0; mi < 4; mi++)
#pragma unroll
        for (int r = 0; r < 4; r++) {
            float* rp = C + (size_t)(m0 + wm + mi * 16 + quad * 4 + r) * ldc + n0 + wn + mm;
#pragma unroll
            for (int ni = 0; ni < 4; ni++) rp[ni * 16] = acc[mi][ni][r];
        }
}

// ---------------- flash attention v12 (known-good ~86us) --------
// Occupancy axis CLOSED at 16 waves/CU: true unified footprint ~128 regs
// (arch 64 + AGPR accs); 8 waves/SIMD forces spill (R9: 2.8 GB scratch).
// Fixed-max softmax (C-init -10, log2 domain). Qb pre-scaled by 0.125*log2e.

template <int SPLIT>
__global__ __launch_bounds__(512, 4) void attn_fwd(const u16* __restrict__ Qb,
                                                   const u16* __restrict__ Kb,
                                                   const u16* __restrict__ Vtb,
                                                   u16* __restrict__ Ob,
                                                   float* __restrict__ Of0,
                                                   float* __restrict__ Of1,
                                                   float* __restrict__ Lf) {
    __shared__ __align__(16) u16 Ks[2][64 * 64];   // [buf][key][dim] swizzled
    __shared__ __align__(16) u16 Vs[2][64 * 64];   // [buf][dim][key] swizzled

    const int qtb = blockIdx.x, head = blockIdx.y;
    const int b = blockIdx.z & 1, sp = blockIdx.z >> 1;
    const int kvh = head >> 2;
    const int wave = threadIdx.x >> 6, lane = threadIdx.x & 63;
    const int h = lane >> 5;          // lane half
    const int q32 = lane & 31;        // query within wave tile
    const int t = threadIdx.x;

    const size_t qrow0 = (size_t)b * 2048 + qtb * 256 + wave * 32;
    const int s_beg = sp * (2048 / SPLIT), s_end = s_beg + 2048 / SPLIT;

    // Q fragments (B-operand: col = q32, k = s*16 + h*8 + j), whole kernel
    half8 qf[4];
#pragma unroll
    for (int s = 0; s < 4; s++)
        qf[s] = *(const half8*)(Qb + (qrow0 + q32) * 2048 + head * 64 + s * 16 + h * 8);

    f32x16 accO[2] = {};
    float lpq[4] = {0.f, 0.f, 0.f, 0.f};

    f32x16 NEG10;
#pragma unroll
    for (int i = 0; i < 16; i++) NEG10[i] = -10.f;

    // staging: 512 threads cover the full 64x64 tile: thread t -> LDS bytes
    // t*16, i.e. row t>>3, physical chunk t&7. Source pre-swizzled:
    // logical chunk (t&7)^((t>>3)&7). ONE async16 each for K and V.
    const int srow = t >> 3;
    const int lch = (t & 7) ^ (srow & 7);
    const u16* kg = Kb + ((size_t)b * 2048 + srow) * 512 + kvh * 64 + lch * 8;
    const u16* vg = Vtb + ((size_t)kvh * 64 + srow) * 4096 + b * 2048 + lch * 8;

#define STAGE(buf, s0)                                                        \
    {                                                                         \
        async16(kg + (size_t)(s0) * 512, &Ks[buf][t * 8]);                    \
        async16(vg + (s0), &Vs[buf][t * 8]);                                  \
    }

    int cur = 0;
    STAGE(0, s_beg);

    const int r0 = q32, r1 = 32 + q32;
    const int sw0 = (r0 & 7), sw1 = (r1 & 7);

    for (int s0 = s_beg; s0 < s_end; s0 += 64) {
        __syncthreads();   // drains vmcnt (DMA done) + barrier (readers done)
        int sn = s0 + 64;
        if (sn < s_end) STAGE(cur ^ 1, sn);

        const u16* Kc = &Ks[cur][0];
        const u16* Vc = &Vs[cur][0];
        const u16* Kr0 = Kc + r0 * 64;
        const u16* Kr1 = Kc + r1 * 64;

        // ---- S^T = K Q^T, both 32-key halves, interleaved chains ----
        // s=0 peeled: C operand = NEG10 constant (no accumulator init movs)
        f32x16 a0, a1;
        __builtin_amdgcn_s_setprio(1);
        {
            half8 k0 = *(const half8*)(Kr0 + ((h ^ sw0) << 3));
            a0 = __builtin_amdgcn_mfma_f32_32x32x16_f16(k0, qf[0], NEG10, 0, 0, 0);
            half8 k1 = *(const half8*)(Kr1 + ((h ^ sw1) << 3));
            a1 = __builtin_amdgcn_mfma_f32_32x32x16_f16(k1, qf[0], NEG10, 0, 0, 0);
        }
#pragma unroll
        for (int s = 1; s < 4; s++) {
            half8 k0 = *(const half8*)(Kr0 + (((2 * s + h) ^ sw0) << 3));
            a0 = __builtin_amdgcn_mfma_f32_32x32x16_f16(k0, qf[s], a0, 0, 0, 0);
            half8 k1 = *(const half8*)(Kr1 + (((2 * s + h) ^ sw1) << 3));
            a1 = __builtin_amdgcn_mfma_f32_32x32x16_f16(k1, qf[s], a1, 0, 0, 0);
        }
        __builtin_amdgcn_s_setprio(0);

        // ---- softmax half 0: p = 2^S, pack f16 pairs ----
        u32 w0[8];
#pragma unroll
        for (int m = 0; m < 8; m++) {
            w0[m] = pk2h(fexp2(a0[2 * m]), fexp2(a0[2 * m + 1]));
            lpq[m & 3] = dot2acc(w0[m], lpq[m & 3]);
        }

        // ---- PV half 0 (ks = 0,1) ----
        __builtin_amdgcn_s_setprio(1);
#pragma unroll
        for (int k1 = 0; k1 < 2; k1++) {
            const int ks = k1;
            u32 d0 = w0[4 * k1 + 0], d2 = w0[4 * k1 + 2];
            u32 d1 = w0[4 * k1 + 1], d3 = w0[4 * k1 + 3];
            plswap(d0, d2);
            plswap(d1, d3);
            u32x4 pd = { d0, d1, d2, d3 };
            half8 pf = __builtin_bit_cast(half8, pd);
#pragma unroll
            for (int dt = 0; dt < 2; dt++) {
                const int rv = dt * 32 + q32;
                half8 vf = *(const half8*)(&Vc[rv * 64 + (((2 * ks + h) ^ (rv & 7)) << 3)]);
                accO[dt] = __builtin_amdgcn_mfma_f32_32x32x16_f16(vf, pf, accO[dt], 0, 0, 0);
            }
        }
        __builtin_amdgcn_s_setprio(0);

        // ---- softmax half 1 (independent of PV0 -> runs in its shadow) ----
        u32 w1[8];
#pragma unroll
        for (int m = 0; m < 8; m++) {
            w1[m] = pk2h(fexp2(a1[2 * m]), fexp2(a1[2 * m + 1]));
            lpq[m & 3] = dot2acc(w1[m], lpq[m & 3]);
        }

        // ---- PV half 1 (ks = 2,3) ----
        __builtin_amdgcn_s_setprio(1);
#pragma unroll
        for (int k1 = 0; k1 < 2; k1++) {
            const int ks = 2 + k1;
            u32 d0 = w1[4 * k1 + 0], d2 = w1[4 * k1 + 2];
            u32 d1 = w1[4 * k1 + 1], d3 = w1[4 * k1 + 3];
            plswap(d0, d2);
            plswap(d1, d3);
            u32x4 pd = { d0, d1, d2, d3 };
            half8 pf = __builtin_bit_cast(half8, pd);
#pragma unroll
            for (int dt = 0; dt < 2; dt++) {
                const int rv = dt * 32 + q32;
                half8 vf = *(const half8*)(&Vc[rv * 64 + (((2 * ks + h) ^ (rv & 7)) << 3)]);
                accO[dt] = __builtin_amdgcn_mfma_f32_32x32x16_f16(vf, pf, accO[dt], 0, 0, 0);
            }
        }
        __builtin_amdgcn_s_setprio(0);

        cur ^= 1;
    }
#undef STAGE

    // l: lane holds one half of the keys; pair lane^32 holds the other
    float l = (lpq[0] + lpq[1]) + (lpq[2] + lpq[3]);
    l += __shfl_xor(l, 32);

    const size_t token = qrow0 + q32;
    if (SPLIT == 1) {
        float inv = 1.f / l;
#pragma unroll
        for (int dt = 0; dt < 2; dt++)
#pragma unroll
            for (int rq = 0; rq < 4; rq++) {
                u16x4 o = { f2h(accO[dt][4 * rq + 0] * inv), f2h(accO[dt][4 * rq + 1] * inv),
                            f2h(accO[dt][4 * rq + 2] * inv), f2h(accO[dt][4 * rq + 3] * inv) };
                *(u16x4*)(Ob + token * 2048 + head * 64 + dt * 32 + rq * 8 + h * 4) = o;
            }
    } else {
        float* Op = sp ? Of1 : Of0;
#pragma unroll
        for (int dt = 0; dt < 2; dt++)
#pragma unroll
            for (int rq = 0; rq < 4; rq++) {
                f32x4 o = { accO[dt][4 * rq + 0], accO[dt][4 * rq + 1],
                            accO[dt][4 * rq + 2], accO[dt][4 * rq + 3] };
                *(f32x4*)(Op + token * 2048 + head * 64 + dt * 32 + rq * 8 + h * 4) = o;
            }
        if (!h) Lf[((size_t)sp * 4096 + token) * 32 + head] = l;
    }
}

// ---------------- launch ----------------

extern "C" void kernel_launch(void* const* d_in, const int* in_sizes, int n_in,
                              void* d_out, int out_size, void* d_ws, size_t ws_size,
                              hipStream_t stream) {
    (void)in_sizes; (void)n_in; (void)out_size; (void)ws_size;
    const float* x  = (const float*)d_in[0];
    const float* Wq = (const float*)d_in[1];
    const float* Wk = (const float*)d_in[2];
    const float* Wv = (const float*)d_in[3];
    const float* Wo = (const float*)d_in[4];
    float* out = (float*)d_out;

    u16* ws = (u16*)d_ws;
    u16* xb   = ws;                              // [4096][2048]
    u16* Wqt  = xb   + (size_t)4096 * 2048;      // [2048][2048]  \ contiguous 3072-row
    u16* Wkvt = Wqt  + (size_t)2048 * 2048;      // [1024][2048]  / B^T for fused QKV
    u16* Wot  = Wkvt + (size_t)1024 * 2048;      // [2048][2048]
    u16* Qb   = Wot  + (size_t)2048 * 2048;      // [4096][2048]
    u16* Kb   = Qb   + (size_t)4096 * 2048;      // [4096][512]
    u16* Vtb  = Kb   + (size_t)4096 * 512;       // [512][4096] (= Kb + 4096*512, OUTMODE 3)
    u16* Ob   = Vtb  + (size_t)512 * 4096;       // [4096][2048]

    // fold softmax scale (1/8) and log2(e) into Wq
    const float qscale = 0.125f * 1.4426950408889634f;

    // fused prologue: x cast + 4 weight transposes, one dispatch
    prep_inputs<<<dim3(64, 64, 5), 256, 0, stream>>>(x, xb, Wq, Wk, Wv, Wo,
                                                     Wqt, Wkvt, Wot, qscale);

    // fused QKV projection: N = 2048 (Q) + 512 (K) + 512 (V) = 3072
    gemm_bt<3><<<dim3(32, 24), 256, 0, stream>>>(xb, Wqt, Qb, Kb, 4096, 3072, 2048, 2048);

    attn_fwd<1><<<dim3(8, 32, 2), 512, 0, stream>>>(Qb, Kb, Vtb, Ob,
                                                    nullptr, nullptr, nullptr);

    // Wo projection: BK=64 variant (grid-capped at 2/CU -> BK=64 is free)
    gemm_wo<<<dim3(32, 16), 256, 0, stream>>>(Ob, Wot, out, 4096, 2048, 2048, 2048);
}